// Round 3
// baseline (215.835 us; speedup 1.0000x reference)
//
#include <hip/hip_runtime.h>
#include <stdint.h>

// SelfCrossAttn bf16-MFMA pipeline v8. b=4, c=512, N=4096, HEADS=4.
// All GEMMs NT: C[m][n] = sum_k A[m][k]*B[n][k], operands k-contiguous.
// kk' = s*128+t permutation (s=n>>10, t=c&127) applied uniformly to P cols
// and vT' rows; sum over kk is order-agnostic.
//  prep    : W* fp32->bf16 (Wb) ; x[b][c][n] -> xT[b][n][c] bf16
//  gemm_qkv: v6 128^2 2-phase core (reverted from failed 256^2 8-phase v7)
//  gemm_qks: NEW fused S=Q.K^T (K=1024) + row softmax -> P bf16.
//            Register-direct operands (no LDS, no K-loop barriers): B rows
//            are wave-exclusive, A panel is 32 rows. S never touches HBM.
//  gemm_pv : O = P.V' (A=P[qq][kk'], B=vT'[e][kk']); scatters into yT[n][c]
//  gemm_proj: out = Wproj @ y + bias + x (NT vs yT), fp32

typedef __attribute__((ext_vector_type(8))) short short8;
typedef __attribute__((ext_vector_type(4))) float f32x4;

typedef const __attribute__((address_space(1))) unsigned int* gas_ptr;
typedef __attribute__((address_space(3))) unsigned int* las_ptr;

#define ATTN_SCALE 0.08838834764831845f   // 128^-0.5

__device__ __forceinline__ unsigned short f2bf(float f) {
    union { float f; unsigned int u; } c; c.f = f;
    unsigned int u = c.u;
    u += 0x7fffu + ((u >> 16) & 1u);      // RNE
    return (unsigned short)(u >> 16);
}

__device__ __forceinline__ void gl_lds16(const void* g, void* l) {
    __builtin_amdgcn_global_load_lds((gas_ptr)(uintptr_t)g, (las_ptr)(uintptr_t)l,
                                     16, 0, 0);
}

// ---- v6 shared MFMA core: 128x128 C-tile, 4 waves, BK=32, 16x16x32 bf16 ----
// Double-buffered (sA/sB each hold 2 x 128x32 tiles = 8192 shorts).
// PERMB: B rows are logical kk' -> physical slab row 4*(kk'&127) + (kk'>>7).
template<int LDA, int LDB, int KDIM, bool PERMB = false>
__device__ __forceinline__ void mfma_core(
    const unsigned short* __restrict__ A,
    const unsigned short* __restrict__ B,
    int m0, int n0,
    unsigned short* __restrict__ sA, unsigned short* __restrict__ sB,
    f32x4 acc[4][4])
{
    const int tid  = threadIdx.x;
    const int lane = tid & 63, wave = tid >> 6;
    const int lr = lane >> 2, lc = lane & 3;       // staging: 16 rows x 4 chunks
    const int lcs = lc ^ ((lr >> 1) & 3);          // source-chunk swizzle
    const int wm = (wave & 1) * 64, wn = (wave >> 1) * 64;
    const int col = lane & 15, quad = lane >> 4;
    const int swz = (quad ^ ((col >> 1) & 3)) * 8; // read-side swizzle (shorts)

    const unsigned short* ga = A + (size_t)(m0 + 32 * wave + lr) * LDA + lcs * 8;
    int rb0 = n0 + 32 * wave + lr;
    int rb1 = rb0 + 16;
    if (PERMB) {
        rb0 = 4 * (rb0 & 127) + (rb0 >> 7);
        rb1 = 4 * (rb1 & 127) + (rb1 >> 7);
    }
    const unsigned short* gb0 = B + (size_t)rb0 * LDB + lcs * 8;
    const unsigned short* gb1 = B + (size_t)rb1 * LDB + lcs * 8;

    const int wr0 = (32 * wave) * 32;              // wave-uniform LDS row bases
    const int wr1 = (32 * wave + 16) * 32;

    // prologue: stage K-step 0 into buffer 0
    gl_lds16(ga,            sA + wr0);
    gl_lds16(ga + 16 * LDA, sA + wr1);
    gl_lds16(gb0,           sB + wr0);
    gl_lds16(gb1,           sB + wr1);

    constexpr int NK = KDIM / 32;
    for (int kk = 0; kk < NK; ++kk) {
        const int bo = (kk & 1) * 4096;
        if (kk + 1 < NK) {
            const int nb = ((kk + 1) & 1) * 4096;
            const int k0 = (kk + 1) * 32;
            gl_lds16(ga + k0,            sA + nb + wr0);
            gl_lds16(ga + k0 + 16 * LDA, sA + nb + wr1);
            gl_lds16(gb0 + k0,           sB + nb + wr0);
            gl_lds16(gb1 + k0,           sB + nb + wr1);
            asm volatile("s_waitcnt vmcnt(4)" ::: "memory");
        } else {
            asm volatile("s_waitcnt vmcnt(0)" ::: "memory");
        }
        __builtin_amdgcn_s_barrier();
        asm volatile("" ::: "memory");
        __builtin_amdgcn_sched_barrier(0);

        const unsigned short* bA = sA + bo;
        const unsigned short* bB = sB + bo;
        short8 af[4], bfv[4];
        #pragma unroll
        for (int i = 0; i < 4; ++i)
            af[i] = *(const short8*)&bA[(wm + i * 16 + col) * 32 + swz];
        #pragma unroll
        for (int j = 0; j < 4; ++j)
            bfv[j] = *(const short8*)&bB[(wn + j * 16 + col) * 32 + swz];
        #pragma unroll
        for (int i = 0; i < 4; ++i)
            #pragma unroll
            for (int j = 0; j < 4; ++j)
                acc[i][j] = __builtin_amdgcn_mfma_f32_16x16x32_bf16(
                    af[i], bfv[j], acc[i][j], 0, 0, 0);

        __builtin_amdgcn_s_barrier();          // reads done before next stage
        asm volatile("" ::: "memory");
    }
}

// ---- prep: z<4 -> transpose x[b][c][n]->xT[b][n][c] bf16 ; z==4 -> W conv ----
__global__ __launch_bounds__(256)
void prep(const float* __restrict__ x,
          const float* __restrict__ Wq, const float* __restrict__ Wk,
          const float* __restrict__ Wv, const float* __restrict__ Wp,
          unsigned short* __restrict__ xT, unsigned short* __restrict__ Wb)
{
    if (blockIdx.z == 4) {
        const int idx = (blockIdx.y * 64 + blockIdx.x) * 256 + threadIdx.x; // 262144
        const int mat = idx >> 16;
        const int off = (idx & 65535) << 2;
        const float* src = (mat == 0 ? Wq : mat == 1 ? Wk : mat == 2 ? Wv : Wp) + off;
        const float4 f = *(const float4*)src;
        uint2 o;
        o.x = f2bf(f.x) | ((unsigned)f2bf(f.y) << 16);
        o.y = f2bf(f.z) | ((unsigned)f2bf(f.w) << 16);
        *(uint2*)&Wb[mat * 262144 + off] = o;
        return;
    }
    const int b = blockIdx.z;
    const int l = threadIdx.x & 63, w = threadIdx.x >> 6;
    const int n  = blockIdx.x * 64 + l;
    const int c0 = blockIdx.y * 32 + w * 8;
    const float* xp = x + (size_t)b * 2097152 + (size_t)c0 * 4096 + n;
    unsigned int p[4];
    #pragma unroll
    for (int j = 0; j < 4; ++j) {
        const unsigned short a  = f2bf(xp[(2 * j)     * 4096]);
        const unsigned short bb = f2bf(xp[(2 * j + 1) * 4096]);
        p[j] = a | ((unsigned)bb << 16);
    }
    uint4 v; v.x = p[0]; v.y = p[1]; v.z = p[2]; v.w = p[3];
    *(uint4*)&xT[(size_t)b * 2097152 + (size_t)n * 512 + c0] = v;
}

// ---- K1: q/k = W @ x natural [o][n]; V direct-stored as vT'[slab][e][kk'] ----
__global__ __launch_bounds__(256)
void gemm_qkv(const unsigned short* __restrict__ Wb,
              const unsigned short* __restrict__ xT,
              unsigned short* __restrict__ qb, unsigned short* __restrict__ kb,
              unsigned short* __restrict__ vT)
{
    __shared__ unsigned short sA[2 * 128 * 32], sB[2 * 128 * 32];

    const int z = blockIdx.z, wsel = z >> 2, b = z & 3;
    const unsigned short* A = Wb + wsel * 262144;
    const unsigned short* B = xT + (size_t)b * 2097152;
    const int m0 = blockIdx.y * 128, n0 = blockIdx.x * 128;

    f32x4 z4 = {0.f, 0.f, 0.f, 0.f};
    f32x4 acc[4][4];
    #pragma unroll
    for (int i = 0; i < 4; ++i)
        #pragma unroll
        for (int j = 0; j < 4; ++j) acc[i][j] = z4;

    mfma_core<512, 512, 512>(A, B, m0, n0, sA, sB, acc);

    const int lane = threadIdx.x & 63, wave = threadIdx.x >> 6;
    const int wm = (wave & 1) * 64, wn = (wave >> 1) * 64;
    const int col = lane & 15, quad = lane >> 4;

    if (wsel < 2) {
        unsigned short* C = (wsel == 0 ? qb : kb) + (size_t)b * 2097152;
        #pragma unroll
        for (int i = 0; i < 4; ++i)
            #pragma unroll
            for (int r = 0; r < 4; ++r) {
                const int row = m0 + wm + i * 16 + quad * 4 + r;
                #pragma unroll
                for (int j = 0; j < 4; ++j)
                    C[(size_t)row * 4096 + n0 + wn + j * 16 + col] = f2bf(acc[i][j][r]);
            }
    } else {
        // V tile: m = channel c -> head h = m0>>7, t = m&127;
        // n -> s = n0>>10 (const per block), e = (n0&1023) + nl.
        // Lane tile (i,j): 4 acc rows = 4 consecutive kk' = wm+i*16+quad*4+r.
        // Direct uint2 store: vT'[b*4+h][e][kk'_base], no LDS round-trip.
        const int h = m0 >> 7, s = n0 >> 10, e0 = n0 & 1023;
        unsigned short* dst = vT + (size_t)(b * 4 + h) * 524288 + s * 128;
        #pragma unroll
        for (int i = 0; i < 4; ++i) {
            const int kb2 = wm + i * 16 + quad * 4;
            #pragma unroll
            for (int j = 0; j < 4; ++j) {
                const int e = e0 + wn + j * 16 + col;
                uint2 o;
                o.x = f2bf(acc[i][j][0]) | ((unsigned)f2bf(acc[i][j][1]) << 16);
                o.y = f2bf(acc[i][j][2]) | ((unsigned)f2bf(acc[i][j][3]) << 16);
                *(uint2*)&dst[(size_t)e * 512 + kb2] = o;
            }
        }
    }
}

// ---- K2 v8: fused S = Q.K^T (K=1024) + row softmax -> P bf16 ----
// Block: 32 qq-rows x 512 kk'-cols, 4 waves (1x4, wave tile 32x128).
// Register-direct operands: no LDS staging, no K-loop barriers.
// q/k chunk for slab z=b*4+h: qb + z*524288, row m=qq at m*1024 + e.
// B col kk' fetched at physical row 4*(kk'&127)+(kk'>>7) (same perm as vT).
// Grid 256 blocks = 16 row-groups x 16 slabs; XCD-chunked (each XCD: 2 slabs).
__global__ __launch_bounds__(256)
void gemm_qks(const unsigned short* __restrict__ qb,
              const unsigned short* __restrict__ kb,
              unsigned short* __restrict__ P)
{
    __shared__ float red[2][32][4];
    const int d = blockIdx.x + 16 * blockIdx.y;       // 0..255
    const int flat = (d & 7) * 32 + (d >> 3);         // XCD-chunked remap
    const int rg = flat & 15, z = flat >> 4;          // row-group, slab
    const unsigned short* Aq = qb + (size_t)z * 524288;
    const unsigned short* Bk = kb + (size_t)z * 524288;
    unsigned short* Pz = P + (size_t)z * 262144;

    const int lane = threadIdx.x & 63, w = threadIdx.x >> 6;
    const int col = lane & 15, quad = lane >> 4;

    const unsigned short* a0 = Aq + (size_t)(rg * 32 + col) * 1024 + quad * 8;
    const unsigned short* a1 = a0 + 16 * 1024;
    const unsigned short* bp[8];
    #pragma unroll
    for (int g = 0; g < 8; ++g) {
        const int n = w * 128 + g * 16 + col;          // kk' logical
        const int r = 4 * (n & 127) + (n >> 7);        // physical row
        bp[g] = Bk + (size_t)r * 1024 + quad * 8;
    }

    f32x4 z4 = {0.f, 0.f, 0.f, 0.f};
    f32x4 acc[2][8];
    #pragma unroll
    for (int f = 0; f < 2; ++f)
        #pragma unroll
        for (int g = 0; g < 8; ++g) acc[f][g] = z4;

    #pragma unroll 2
    for (int k0 = 0; k0 < 1024; k0 += 32) {
        const short8 af0 = *(const short8*)(a0 + k0);
        const short8 af1 = *(const short8*)(a1 + k0);
        short8 bf[8];
        #pragma unroll
        for (int g = 0; g < 8; ++g) bf[g] = *(const short8*)(bp[g] + k0);
        #pragma unroll
        for (int g = 0; g < 8; ++g)
            acc[0][g] = __builtin_amdgcn_mfma_f32_16x16x32_bf16(
                af0, bf[g], acc[0][g], 0, 0, 0);
        #pragma unroll
        for (int g = 0; g < 8; ++g)
            acc[1][g] = __builtin_amdgcn_mfma_f32_16x16x32_bf16(
                af1, bf[g], acc[1][g], 0, 0, 0);
    }

    // ---- fused softmax over full 512-wide rows ----
    // lane owns rows f*16 + quad*4 + r, cols w*128 + g*16 + col.
    float mx[2][4];
    #pragma unroll
    for (int f = 0; f < 2; ++f)
        #pragma unroll
        for (int r = 0; r < 4; ++r) {
            float m = acc[f][0][r];
            #pragma unroll
            for (int g = 1; g < 8; ++g) m = fmaxf(m, acc[f][g][r]);
            #pragma unroll
            for (int s = 1; s < 16; s <<= 1) m = fmaxf(m, __shfl_xor(m, s));
            mx[f][r] = m;
        }
    if (col == 0) {
        #pragma unroll
        for (int f = 0; f < 2; ++f)
            #pragma unroll
            for (int r = 0; r < 4; ++r)
                red[0][f * 16 + quad * 4 + r][w] = mx[f][r];
    }
    __syncthreads();
    float sm[2][4];
    #pragma unroll
    for (int f = 0; f < 2; ++f)
        #pragma unroll
        for (int r = 0; r < 4; ++r) {
            const int row = f * 16 + quad * 4 + r;
            const float m = fmaxf(fmaxf(red[0][row][0], red[0][row][1]),
                                  fmaxf(red[0][row][2], red[0][row][3]));
            float s = 0.f;
            #pragma unroll
            for (int g = 0; g < 8; ++g) {
                const float e = __expf((acc[f][g][r] - m) * ATTN_SCALE);
                acc[f][g][r] = e;
                s += e;
            }
            #pragma unroll
            for (int t = 1; t < 16; t <<= 1) s += __shfl_xor(s, t);
            sm[f][r] = s;
        }
    if (col == 0) {
        #pragma unroll
        for (int f = 0; f < 2; ++f)
            #pragma unroll
            for (int r = 0; r < 4; ++r)
                red[1][f * 16 + quad * 4 + r][w] = sm[f][r];
    }
    __syncthreads();
    #pragma unroll
    for (int f = 0; f < 2; ++f)
        #pragma unroll
        for (int r = 0; r < 4; ++r) {
            const int row = f * 16 + quad * 4 + r;
            const float tot = red[1][row][0] + red[1][row][1]
                            + red[1][row][2] + red[1][row][3];
            const float inv = 1.f / tot;
            unsigned short* op = Pz + (size_t)(rg * 32 + row) * 512
                               + w * 128 + col;
            #pragma unroll
            for (int g = 0; g < 8; ++g)
                op[g * 16] = f2bf(acc[f][g][r] * inv);
        }
}

// ---- K4: O = P V' per slab; scatter into yT[n][c] via LDS tile ----
__global__ __launch_bounds__(256)
void gemm_pv(const unsigned short* __restrict__ Pb,
             const unsigned short* __restrict__ vT,
             unsigned short* __restrict__ yT)
{
    __shared__ unsigned short sT[128 * 136];          // 34816 B; aliases staging
    unsigned short* sA = sT;                          // [2][128*32] = 8192
    unsigned short* sB = sT + 8192;                   // [2][128*32] = 8192
    const int z = blockIdx.z, b = z >> 2, hh = z & 3;
    const unsigned short* A = Pb + (size_t)z * 262144;   // [512][512] kk'-cols
    const unsigned short* B = vT + (size_t)z * 524288;   // [1024][512] kk'-rows
    unsigned short* yTb = yT + (size_t)b * 2097152;
    const int m0 = blockIdx.y * 128;   // qq
    const int n0 = blockIdx.x * 128;   // e

    f32x4 z4 = {0.f, 0.f, 0.f, 0.f};
    f32x4 acc[4][4];
    #pragma unroll
    for (int i = 0; i < 4; ++i)
        #pragma unroll
        for (int j = 0; j < 4; ++j) acc[i][j] = z4;

    mfma_core<512, 512, 512>(A, B, m0, n0, sA, sB, acc);

    // full drain before overwriting the aliased staging buffers with D-tile
    __syncthreads();

    const int tid = threadIdx.x;
    const int lane = tid & 63, wave = tid >> 6;
    const int wm = (wave & 1) * 64, wn = (wave >> 1) * 64;
    const int col = lane & 15, quad = lane >> 4;

    // D tile -> LDS [qq_local][e_local], pad 136
    #pragma unroll
    for (int i = 0; i < 4; ++i)
        #pragma unroll
        for (int r = 0; r < 4; ++r) {
            const int rr = wm + i * 16 + quad * 4 + r;
            #pragma unroll
            for (int j = 0; j < 4; ++j)
                sT[rr * 136 + wn + j * 16 + col] = f2bf(acc[i][j][r]);
        }
    __syncthreads();

    // pack 16-elem c-runs: yT[(s<<9)+qq][hh*128 + (n0>>3) + tt], tt=0..15
    #pragma unroll
    for (int k = 0; k < 4; ++k) {
        const int rid = k * 256 + tid;       // 0..1023
        const int qq_l = rid >> 3, s = rid & 7;
        const unsigned short* Trow = sT + qq_l * 136;
        unsigned int p[8];
        #pragma unroll
        for (int t = 0; t < 8; ++t) {
            const unsigned int a  = Trow[s + 8 * (2 * t)];
            const unsigned int bb = Trow[s + 8 * (2 * t + 1)];
            p[t] = a | (bb << 16);
        }
        const size_t base = (size_t)((s << 9) + m0 + qq_l) * 512 + hh * 128 + (n0 >> 3);
        uint4 lo; lo.x = p[0]; lo.y = p[1]; lo.z = p[2]; lo.w = p[3];
        uint4 hi; hi.x = p[4]; hi.y = p[5]; hi.z = p[6]; hi.w = p[7];
        *(uint4*)&yTb[base]     = lo;
        *(uint4*)&yTb[base + 8] = hi;
    }
}

// ---- K5: out = Wproj @ y + bias + x (NT vs yT), fp32 out ----
__global__ __launch_bounds__(256)
void gemm_proj(const unsigned short* __restrict__ Wpb,
               const unsigned short* __restrict__ yT,
               const float* __restrict__ bias, const float* __restrict__ x,
               float* __restrict__ out)
{
    __shared__ unsigned short sA[2 * 128 * 32], sB[2 * 128 * 32];
    const int b = blockIdx.z;
    const unsigned short* B = yT + (size_t)b * 2097152;  // [4096][512]
    const int m0 = blockIdx.y * 128, n0 = blockIdx.x * 128;

    f32x4 z4 = {0.f, 0.f, 0.f, 0.f};
    f32x4 acc[4][4];
    #pragma unroll
    for (int i = 0; i < 4; ++i)
        #pragma unroll
        for (int j = 0; j < 4; ++j) acc[i][j] = z4;

    mfma_core<512, 512, 512>(Wpb, B, m0, n0, sA, sB, acc);

    const int lane = threadIdx.x & 63, wave = threadIdx.x >> 6;
    const int wm = (wave & 1) * 64, wn = (wave >> 1) * 64;
    const int col = lane & 15, quad = lane >> 4;
    const size_t boff = (size_t)b * 2097152;
    #pragma unroll
    for (int i = 0; i < 4; ++i)
        #pragma unroll
        for (int r = 0; r < 4; ++r) {
            const int row = m0 + wm + i * 16 + quad * 4 + r;
            const float bi = bias[row];
            #pragma unroll
            for (int j = 0; j < 4; ++j) {
                const size_t idx = boff + (size_t)row * 4096 + n0 + wn + j * 16 + col;
                out[idx] = acc[i][j][r] + bi + x[idx];
            }
        }
}

extern "C" void kernel_launch(void* const* d_in, const int* in_sizes, int n_in,
                              void* d_out, int out_size, void* d_ws, size_t ws_size,
                              hipStream_t stream) {
    const float* x     = (const float*)d_in[0];
    const float* Wq    = (const float*)d_in[1];
    const float* Wk    = (const float*)d_in[2];
    const float* Wv    = (const float*)d_in[3];
    const float* Wproj = (const float*)d_in[4];
    const float* bproj = (const float*)d_in[5];
    float* out = (float*)d_out;

    char* w = (char*)d_ws;
    unsigned short* xT = (unsigned short*)(w + 0);          // 16 MB [b][n][c]
    unsigned short* qb = (unsigned short*)(w + 16777216);   // 16 MB [b][o][n]
    unsigned short* kb = (unsigned short*)(w + 33554432);   // 16 MB
    unsigned short* vT = (unsigned short*)(w + 50331648);   // 16 MB [slab][e][kk']
    unsigned short* Pb = (unsigned short*)(w + 100663296);  //  8 MB
    unsigned short* Wb = (unsigned short*)(w + 109051904);  //  2 MB
    unsigned short* yT = xT;   // xT dead after gemm_qkv

    prep        <<<dim3(64, 16, 5),  256, 0, stream>>>(x, Wq, Wk, Wv, Wproj, xT, Wb);
    gemm_qkv    <<<dim3(32, 4, 12),  256, 0, stream>>>(Wb, xT, qb, kb, vT);
    gemm_qks    <<<dim3(16, 16),     256, 0, stream>>>(qb, kb, Pb);
    gemm_pv     <<<dim3(8, 4, 16),   256, 0, stream>>>(Pb, vT, yT);
    gemm_proj   <<<dim3(32, 4, 4),   256, 0, stream>>>(Wb + 3 * 262144, yT, bproj, x, out);
}

// Round 4
// 191.047 us; speedup vs baseline: 1.1298x; 1.1298x over previous
//
#include <hip/hip_runtime.h>
#include <stdint.h>

// SelfCrossAttn bf16-MFMA pipeline v9. b=4, c=512, N=4096, HEADS=4.
// All GEMMs NT: C[m][n] = sum_k A[m][k]*B[n][k], operands k-contiguous.
// kk' = s*128+t permutation (s=n>>10, t=c&127) applied uniformly to P cols
// and vT' rows; sum over kk is order-agnostic.
//  prep    : W* fp32->bf16 (Wb) ; x[b][c][n] -> xT[b][n][c] bf16
//  gemm_qkv: v6 128^2 2-phase core. q/k now stored in FRAGMENT-LINEAR
//            layout (consumed only by gemm_qks): per slab z=b*4+h,
//            frag(R,Kc) at (R*32+Kc)*512 + lane*8, lane=quad*16+col holds
//            row col, k-elems quad*8..+8.  Q rows qq=4t+s natural;
//            K rows kk'=s*128+t (perm baked in).  V as vT'[slab][e][kk'].
//  gemm_qks: fused S=Q.K^T (K=1024) + row softmax -> P bf16.
//            Register-direct COALESCED frag loads (1KB per b128), no LDS
//            staging, no K-loop barriers. 8 waves, 64-col split per wave.
//  gemm_pv : O = P.V' (A=P[qq][kk'], B=vT'[e][kk']); scatters into yT[n][c]
//  gemm_proj: out = Wproj @ y + bias + x (NT vs yT), fp32

typedef __attribute__((ext_vector_type(8))) short short8;
typedef __attribute__((ext_vector_type(4))) float f32x4;

typedef const __attribute__((address_space(1))) unsigned int* gas_ptr;
typedef __attribute__((address_space(3))) unsigned int* las_ptr;

#define ATTN_SCALE 0.08838834764831845f   // 128^-0.5

__device__ __forceinline__ unsigned short f2bf(float f) {
    union { float f; unsigned int u; } c; c.f = f;
    unsigned int u = c.u;
    u += 0x7fffu + ((u >> 16) & 1u);      // RNE
    return (unsigned short)(u >> 16);
}

__device__ __forceinline__ void gl_lds16(const void* g, void* l) {
    __builtin_amdgcn_global_load_lds((gas_ptr)(uintptr_t)g, (las_ptr)(uintptr_t)l,
                                     16, 0, 0);
}

// ---- v6 shared MFMA core: 128x128 C-tile, 4 waves, BK=32, 16x16x32 bf16 ----
// Double-buffered (sA/sB each hold 2 x 128x32 tiles = 8192 shorts).
// PERMB: B rows are logical kk' -> physical slab row 4*(kk'&127) + (kk'>>7).
template<int LDA, int LDB, int KDIM, bool PERMB = false>
__device__ __forceinline__ void mfma_core(
    const unsigned short* __restrict__ A,
    const unsigned short* __restrict__ B,
    int m0, int n0,
    unsigned short* __restrict__ sA, unsigned short* __restrict__ sB,
    f32x4 acc[4][4])
{
    const int tid  = threadIdx.x;
    const int lane = tid & 63, wave = tid >> 6;
    const int lr = lane >> 2, lc = lane & 3;       // staging: 16 rows x 4 chunks
    const int lcs = lc ^ ((lr >> 1) & 3);          // source-chunk swizzle
    const int wm = (wave & 1) * 64, wn = (wave >> 1) * 64;
    const int col = lane & 15, quad = lane >> 4;
    const int swz = (quad ^ ((col >> 1) & 3)) * 8; // read-side swizzle (shorts)

    const unsigned short* ga = A + (size_t)(m0 + 32 * wave + lr) * LDA + lcs * 8;
    int rb0 = n0 + 32 * wave + lr;
    int rb1 = rb0 + 16;
    if (PERMB) {
        rb0 = 4 * (rb0 & 127) + (rb0 >> 7);
        rb1 = 4 * (rb1 & 127) + (rb1 >> 7);
    }
    const unsigned short* gb0 = B + (size_t)rb0 * LDB + lcs * 8;
    const unsigned short* gb1 = B + (size_t)rb1 * LDB + lcs * 8;

    const int wr0 = (32 * wave) * 32;              // wave-uniform LDS row bases
    const int wr1 = (32 * wave + 16) * 32;

    // prologue: stage K-step 0 into buffer 0
    gl_lds16(ga,            sA + wr0);
    gl_lds16(ga + 16 * LDA, sA + wr1);
    gl_lds16(gb0,           sB + wr0);
    gl_lds16(gb1,           sB + wr1);

    constexpr int NK = KDIM / 32;
    for (int kk = 0; kk < NK; ++kk) {
        const int bo = (kk & 1) * 4096;
        if (kk + 1 < NK) {
            const int nb = ((kk + 1) & 1) * 4096;
            const int k0 = (kk + 1) * 32;
            gl_lds16(ga + k0,            sA + nb + wr0);
            gl_lds16(ga + k0 + 16 * LDA, sA + nb + wr1);
            gl_lds16(gb0 + k0,           sB + nb + wr0);
            gl_lds16(gb1 + k0,           sB + nb + wr1);
            asm volatile("s_waitcnt vmcnt(4)" ::: "memory");
        } else {
            asm volatile("s_waitcnt vmcnt(0)" ::: "memory");
        }
        __builtin_amdgcn_s_barrier();
        asm volatile("" ::: "memory");
        __builtin_amdgcn_sched_barrier(0);

        const unsigned short* bA = sA + bo;
        const unsigned short* bB = sB + bo;
        short8 af[4], bfv[4];
        #pragma unroll
        for (int i = 0; i < 4; ++i)
            af[i] = *(const short8*)&bA[(wm + i * 16 + col) * 32 + swz];
        #pragma unroll
        for (int j = 0; j < 4; ++j)
            bfv[j] = *(const short8*)&bB[(wn + j * 16 + col) * 32 + swz];
        #pragma unroll
        for (int i = 0; i < 4; ++i)
            #pragma unroll
            for (int j = 0; j < 4; ++j)
                acc[i][j] = __builtin_amdgcn_mfma_f32_16x16x32_bf16(
                    af[i], bfv[j], acc[i][j], 0, 0, 0);

        __builtin_amdgcn_s_barrier();          // reads done before next stage
        asm volatile("" ::: "memory");
    }
}

// ---- prep: z<4 -> transpose x[b][c][n]->xT[b][n][c] bf16 ; z==4 -> W conv ----
__global__ __launch_bounds__(256)
void prep(const float* __restrict__ x,
          const float* __restrict__ Wq, const float* __restrict__ Wk,
          const float* __restrict__ Wv, const float* __restrict__ Wp,
          unsigned short* __restrict__ xT, unsigned short* __restrict__ Wb)
{
    if (blockIdx.z == 4) {
        const int idx = (blockIdx.y * 64 + blockIdx.x) * 256 + threadIdx.x; // 262144
        const int mat = idx >> 16;
        const int off = (idx & 65535) << 2;
        const float* src = (mat == 0 ? Wq : mat == 1 ? Wk : mat == 2 ? Wv : Wp) + off;
        const float4 f = *(const float4*)src;
        uint2 o;
        o.x = f2bf(f.x) | ((unsigned)f2bf(f.y) << 16);
        o.y = f2bf(f.z) | ((unsigned)f2bf(f.w) << 16);
        *(uint2*)&Wb[mat * 262144 + off] = o;
        return;
    }
    const int b = blockIdx.z;
    const int l = threadIdx.x & 63, w = threadIdx.x >> 6;
    const int n  = blockIdx.x * 64 + l;
    const int c0 = blockIdx.y * 32 + w * 8;
    const float* xp = x + (size_t)b * 2097152 + (size_t)c0 * 4096 + n;
    unsigned int p[4];
    #pragma unroll
    for (int j = 0; j < 4; ++j) {
        const unsigned short a  = f2bf(xp[(2 * j)     * 4096]);
        const unsigned short bb = f2bf(xp[(2 * j + 1) * 4096]);
        p[j] = a | ((unsigned)bb << 16);
    }
    uint4 v; v.x = p[0]; v.y = p[1]; v.z = p[2]; v.w = p[3];
    *(uint4*)&xT[(size_t)b * 2097152 + (size_t)n * 512 + c0] = v;
}

// ---- K1: q/k = W @ x -> FRAGMENT layout; V direct as vT'[slab][e][kk'] ----
__global__ __launch_bounds__(256)
void gemm_qkv(const unsigned short* __restrict__ Wb,
              const unsigned short* __restrict__ xT,
              unsigned short* __restrict__ qb, unsigned short* __restrict__ kb,
              unsigned short* __restrict__ vT)
{
    __shared__ unsigned short sA[2 * 128 * 32], sB[2 * 128 * 32];

    const int z = blockIdx.z, wsel = z >> 2, b = z & 3;
    const unsigned short* A = Wb + wsel * 262144;
    const unsigned short* B = xT + (size_t)b * 2097152;
    const int m0 = blockIdx.y * 128, n0 = blockIdx.x * 128;

    f32x4 z4 = {0.f, 0.f, 0.f, 0.f};
    f32x4 acc[4][4];
    #pragma unroll
    for (int i = 0; i < 4; ++i)
        #pragma unroll
        for (int j = 0; j < 4; ++j) acc[i][j] = z4;

    mfma_core<512, 512, 512>(A, B, m0, n0, sA, sB, acc);

    const int lane = threadIdx.x & 63, wave = threadIdx.x >> 6;
    const int wm = (wave & 1) * 64, wn = (wave >> 1) * 64;
    const int col = lane & 15, quad = lane >> 4;

    if (wsel < 2) {
        // Fragment-linear store for gemm_qks:
        //  elem (row, e): addr = z*524288 + (R*32 + e>>5)*512
        //                        + (((e>>3)&3)*16 + cc)*8 + (e&7)
        //  Q: row qq = 4t+s  -> R = t>>2,         cc = 4*(t&3)+s
        //  K: row kk'= s*128+t -> R = s*8+(t>>4), cc = t&15
        //  (t = channel&127 = wm+i*16+quad*4+r, s = n>>10 const per block)
        unsigned short* C = (wsel == 0 ? qb : kb)
                          + (size_t)(b * 4 + (m0 >> 7)) * 524288;
        const int s  = n0 >> 10;
        const int e0 = (n0 & 1023) + wn;
        const int tq = wm + quad * 4;
        #pragma unroll
        for (int i = 0; i < 4; ++i) {
            #pragma unroll
            for (int j = 0; j < 4; ++j) {
                const int e  = e0 + j * 16 + col;
                const int Kc = e >> 5, qc = (e >> 3) & 3, el = e & 7;
                #pragma unroll
                for (int r = 0; r < 4; ++r) {
                    const int t = tq + i * 16 + r;
                    int R, cc;
                    if (wsel == 0) { R = t >> 2;           cc = 4 * (t & 3) + s; }
                    else           { R = s * 8 + (t >> 4); cc = t & 15; }
                    C[(R * 32 + Kc) * 512 + (qc * 16 + cc) * 8 + el] =
                        f2bf(acc[i][j][r]);
                }
            }
        }
    } else {
        // V tile: m = channel c -> head h = m0>>7, t = m&127;
        // n -> s = n0>>10 (const per block), e = (n0&1023) + nl.
        // Lane tile (i,j): 4 acc rows = 4 consecutive kk' = wm+i*16+quad*4+r.
        // Direct uint2 store: vT'[b*4+h][e][kk'_base], no LDS round-trip.
        const int h = m0 >> 7, s = n0 >> 10, e0 = n0 & 1023;
        unsigned short* dst = vT + (size_t)(b * 4 + h) * 524288 + s * 128;
        #pragma unroll
        for (int i = 0; i < 4; ++i) {
            const int kb2 = wm + i * 16 + quad * 4;
            #pragma unroll
            for (int j = 0; j < 4; ++j) {
                const int e = e0 + wn + j * 16 + col;
                uint2 o;
                o.x = f2bf(acc[i][j][0]) | ((unsigned)f2bf(acc[i][j][1]) << 16);
                o.y = f2bf(acc[i][j][2]) | ((unsigned)f2bf(acc[i][j][3]) << 16);
                *(uint2*)&dst[(size_t)e * 512 + kb2] = o;
            }
        }
    }
}

// ---- K2 v9: fused S = Q.K^T (K=1024) + row softmax -> P bf16 ----
// Block: 32 qq-rows x 512 kk'-cols, 8 waves (64 cols each).
// Operands in fragment-linear layout: every frag load = one coalesced
// 1KB b128 (lane reads base + lane*16B). No LDS staging, no K-loop
// barriers; ILP via unroll-4. Grid 256 = 16 rg x 16 slabs, XCD-chunked.
__global__ __launch_bounds__(512)
void gemm_qks(const unsigned short* __restrict__ qb,
              const unsigned short* __restrict__ kb,
              unsigned short* __restrict__ P)
{
    __shared__ float red[2][32][8];
    const int d = blockIdx.x;                         // 0..255
    const int flat = (d & 7) * 32 + (d >> 3);         // XCD-chunked remap
    const int rg = flat & 15, z = flat >> 4;          // row-group, slab
    const unsigned short* Aq = qb + (size_t)z * 524288;
    const unsigned short* Bk = kb + (size_t)z * 524288;
    unsigned short* Pz = P + (size_t)z * 262144;

    const int tid = threadIdx.x;
    const int lane = tid & 63, w = tid >> 6;
    const int col = lane & 15, quad = lane >> 4;

    const unsigned short* ap0 = Aq + (size_t)((rg * 2 + 0) * 32) * 512 + lane * 8;
    const unsigned short* ap1 = Aq + (size_t)((rg * 2 + 1) * 32) * 512 + lane * 8;
    const unsigned short* bp0 = Bk + (size_t)((w * 4 + 0) * 32) * 512 + lane * 8;
    const unsigned short* bp1 = bp0 + 16384;
    const unsigned short* bp2 = bp0 + 32768;
    const unsigned short* bp3 = bp0 + 49152;

    f32x4 z4 = {0.f, 0.f, 0.f, 0.f};
    f32x4 acc[2][4];
    #pragma unroll
    for (int f = 0; f < 2; ++f)
        #pragma unroll
        for (int g = 0; g < 4; ++g) acc[f][g] = z4;

    #pragma unroll 4
    for (int kk = 0; kk < 32; ++kk) {
        const int o = kk * 512;
        const short8 af0 = *(const short8*)(ap0 + o);
        const short8 af1 = *(const short8*)(ap1 + o);
        short8 bf[4];
        bf[0] = *(const short8*)(bp0 + o);
        bf[1] = *(const short8*)(bp1 + o);
        bf[2] = *(const short8*)(bp2 + o);
        bf[3] = *(const short8*)(bp3 + o);
        #pragma unroll
        for (int g = 0; g < 4; ++g)
            acc[0][g] = __builtin_amdgcn_mfma_f32_16x16x32_bf16(
                af0, bf[g], acc[0][g], 0, 0, 0);
        #pragma unroll
        for (int g = 0; g < 4; ++g)
            acc[1][g] = __builtin_amdgcn_mfma_f32_16x16x32_bf16(
                af1, bf[g], acc[1][g], 0, 0, 0);
    }

    // ---- fused softmax over full 512-wide rows ----
    // lane owns rows f*16 + quad*4 + r, cols w*64 + g*16 + col.
    float mx[2][4];
    #pragma unroll
    for (int f = 0; f < 2; ++f)
        #pragma unroll
        for (int r = 0; r < 4; ++r) {
            float m = acc[f][0][r];
            #pragma unroll
            for (int g = 1; g < 4; ++g) m = fmaxf(m, acc[f][g][r]);
            #pragma unroll
            for (int s = 1; s < 16; s <<= 1) m = fmaxf(m, __shfl_xor(m, s));
            mx[f][r] = m;
        }
    if (col == 0) {
        #pragma unroll
        for (int f = 0; f < 2; ++f)
            #pragma unroll
            for (int r = 0; r < 4; ++r)
                red[0][f * 16 + quad * 4 + r][w] = mx[f][r];
    }
    __syncthreads();
    float sm[2][4];
    #pragma unroll
    for (int f = 0; f < 2; ++f)
        #pragma unroll
        for (int r = 0; r < 4; ++r) {
            const int row = f * 16 + quad * 4 + r;
            float m = red[0][row][0];
            #pragma unroll
            for (int t = 1; t < 8; ++t) m = fmaxf(m, red[0][row][t]);
            float s = 0.f;
            #pragma unroll
            for (int g = 0; g < 4; ++g) {
                const float e = __expf((acc[f][g][r] - m) * ATTN_SCALE);
                acc[f][g][r] = e;
                s += e;
            }
            #pragma unroll
            for (int t = 1; t < 16; t <<= 1) s += __shfl_xor(s, t);
            sm[f][r] = s;
        }
    if (col == 0) {
        #pragma unroll
        for (int f = 0; f < 2; ++f)
            #pragma unroll
            for (int r = 0; r < 4; ++r)
                red[1][f * 16 + quad * 4 + r][w] = sm[f][r];
    }
    __syncthreads();
    #pragma unroll
    for (int f = 0; f < 2; ++f)
        #pragma unroll
        for (int r = 0; r < 4; ++r) {
            const int row = f * 16 + quad * 4 + r;
            float tot = red[1][row][0];
            #pragma unroll
            for (int t = 1; t < 8; ++t) tot += red[1][row][t];
            const float inv = 1.f / tot;
            unsigned short* op = Pz + (size_t)(rg * 32 + row) * 512
                               + w * 64 + col;
            #pragma unroll
            for (int g = 0; g < 4; ++g)
                op[g * 16] = f2bf(acc[f][g][r] * inv);
        }
}

// ---- K4: O = P V' per slab; scatter into yT[n][c] via LDS tile ----
__global__ __launch_bounds__(256)
void gemm_pv(const unsigned short* __restrict__ Pb,
             const unsigned short* __restrict__ vT,
             unsigned short* __restrict__ yT)
{
    __shared__ unsigned short sT[128 * 136];          // 34816 B; aliases staging
    unsigned short* sA = sT;                          // [2][128*32] = 8192
    unsigned short* sB = sT + 8192;                   // [2][128*32] = 8192
    const int z = blockIdx.z, b = z >> 2, hh = z & 3;
    const unsigned short* A = Pb + (size_t)z * 262144;   // [512][512] kk'-cols
    const unsigned short* B = vT + (size_t)z * 524288;   // [1024][512] kk'-rows
    unsigned short* yTb = yT + (size_t)b * 2097152;
    const int m0 = blockIdx.y * 128;   // qq
    const int n0 = blockIdx.x * 128;   // e

    f32x4 z4 = {0.f, 0.f, 0.f, 0.f};
    f32x4 acc[4][4];
    #pragma unroll
    for (int i = 0; i < 4; ++i)
        #pragma unroll
        for (int j = 0; j < 4; ++j) acc[i][j] = z4;

    mfma_core<512, 512, 512>(A, B, m0, n0, sA, sB, acc);

    // full drain before overwriting the aliased staging buffers with D-tile
    __syncthreads();

    const int tid = threadIdx.x;
    const int lane = tid & 63, wave = tid >> 6;
    const int wm = (wave & 1) * 64, wn = (wave >> 1) * 64;
    const int col = lane & 15, quad = lane >> 4;

    // D tile -> LDS [qq_local][e_local], pad 136
    #pragma unroll
    for (int i = 0; i < 4; ++i)
        #pragma unroll
        for (int r = 0; r < 4; ++r) {
            const int rr = wm + i * 16 + quad * 4 + r;
            #pragma unroll
            for (int j = 0; j < 4; ++j)
                sT[rr * 136 + wn + j * 16 + col] = f2bf(acc[i][j][r]);
        }
    __syncthreads();

    // pack 16-elem c-runs: yT[(s<<9)+qq][hh*128 + (n0>>3) + tt], tt=0..15
    #pragma unroll
    for (int k = 0; k < 4; ++k) {
        const int rid = k * 256 + tid;       // 0..1023
        const int qq_l = rid >> 3, s = rid & 7;
        const unsigned short* Trow = sT + qq_l * 136;
        unsigned int p[8];
        #pragma unroll
        for (int t = 0; t < 8; ++t) {
            const unsigned int a  = Trow[s + 8 * (2 * t)];
            const unsigned int bb = Trow[s + 8 * (2 * t + 1)];
            p[t] = a | (bb << 16);
        }
        const size_t base = (size_t)((s << 9) + m0 + qq_l) * 512 + hh * 128 + (n0 >> 3);
        uint4 lo; lo.x = p[0]; lo.y = p[1]; lo.z = p[2]; lo.w = p[3];
        uint4 hi; hi.x = p[4]; hi.y = p[5]; hi.z = p[6]; hi.w = p[7];
        *(uint4*)&yTb[base]     = lo;
        *(uint4*)&yTb[base + 8] = hi;
    }
}

// ---- K5: out = Wproj @ y + bias + x (NT vs yT), fp32 out ----
__global__ __launch_bounds__(256)
void gemm_proj(const unsigned short* __restrict__ Wpb,
               const unsigned short* __restrict__ yT,
               const float* __restrict__ bias, const float* __restrict__ x,
               float* __restrict__ out)
{
    __shared__ unsigned short sA[2 * 128 * 32], sB[2 * 128 * 32];
    const int b = blockIdx.z;
    const unsigned short* B = yT + (size_t)b * 2097152;  // [4096][512]
    const int m0 = blockIdx.y * 128, n0 = blockIdx.x * 128;

    f32x4 z4 = {0.f, 0.f, 0.f, 0.f};
    f32x4 acc[4][4];
    #pragma unroll
    for (int i = 0; i < 4; ++i)
        #pragma unroll
        for (int j = 0; j < 4; ++j) acc[i][j] = z4;

    mfma_core<512, 512, 512>(Wpb, B, m0, n0, sA, sB, acc);

    const int lane = threadIdx.x & 63, wave = threadIdx.x >> 6;
    const int wm = (wave & 1) * 64, wn = (wave >> 1) * 64;
    const int col = lane & 15, quad = lane >> 4;
    const size_t boff = (size_t)b * 2097152;
    #pragma unroll
    for (int i = 0; i < 4; ++i)
        #pragma unroll
        for (int r = 0; r < 4; ++r) {
            const int row = m0 + wm + i * 16 + quad * 4 + r;
            const float bi = bias[row];
            #pragma unroll
            for (int j = 0; j < 4; ++j) {
                const size_t idx = boff + (size_t)row * 4096 + n0 + wn + j * 16 + col;
                out[idx] = acc[i][j][r] + bi + x[idx];
            }
        }
}

extern "C" void kernel_launch(void* const* d_in, const int* in_sizes, int n_in,
                              void* d_out, int out_size, void* d_ws, size_t ws_size,
                              hipStream_t stream) {
    const float* x     = (const float*)d_in[0];
    const float* Wq    = (const float*)d_in[1];
    const float* Wk    = (const float*)d_in[2];
    const float* Wv    = (const float*)d_in[3];
    const float* Wproj = (const float*)d_in[4];
    const float* bproj = (const float*)d_in[5];
    float* out = (float*)d_out;

    char* w = (char*)d_ws;
    unsigned short* xT = (unsigned short*)(w + 0);          // 16 MB [b][n][c]
    unsigned short* qb = (unsigned short*)(w + 16777216);   // 16 MB frag-layout
    unsigned short* kb = (unsigned short*)(w + 33554432);   // 16 MB frag-layout
    unsigned short* vT = (unsigned short*)(w + 50331648);   // 16 MB [slab][e][kk']
    unsigned short* Pb = (unsigned short*)(w + 100663296);  //  8 MB
    unsigned short* Wb = (unsigned short*)(w + 109051904);  //  2 MB
    unsigned short* yT = xT;   // xT dead after gemm_qkv

    prep        <<<dim3(64, 16, 5),  256, 0, stream>>>(x, Wq, Wk, Wv, Wproj, xT, Wb);
    gemm_qkv    <<<dim3(32, 4, 12),  256, 0, stream>>>(Wb, xT, qb, kb, vT);
    gemm_qks    <<<dim3(256),        512, 0, stream>>>(qb, kb, Pb);
    gemm_pv     <<<dim3(8, 4, 16),   256, 0, stream>>>(Pb, vT, yT);
    gemm_proj   <<<dim3(32, 4, 4),   256, 0, stream>>>(Wb + 3 * 262144, yT, bproj, x, out);
}

// Round 5
// 185.657 us; speedup vs baseline: 1.1625x; 1.0290x over previous
//
#include <hip/hip_runtime.h>
#include <stdint.h>

// SelfCrossAttn bf16-MFMA pipeline v10. b=4, c=512, N=4096, HEADS=4.
// All GEMMs NT: C[m][n] = sum_k A[m][k]*B[n][k], operands k-contiguous.
// STORED row/col order for S/P and vT cols is kk'' = s*128+t (s = n>>10,
// t = ch&127); semantic attn index is 4t+s.  Sum over kk order-agnostic;
// P rows un-permuted only at gemm_pv's yT scatter.
//  prep    : W* fp32->bf16 (Wb) ; x[b][c][n] -> xT[b][n][c] bf16
//  gemm_qkv: v6 128^2 2-phase core. Epilogues via LDS repack:
//            q/k -> FRAGMENT-LINEAR layout (1KB frag = lane*16B), rows in
//            stored order (Q formula == K formula); V -> vT'[slab][e][kk''],
//            all global stores b128 coalesced.
//  gemm_qks: fused S=Q.K^T (K=1024) + row softmax -> P bf16 (stored rows).
//            Register-direct coalesced frag loads, no LDS, no K barriers.
//  gemm_pv : O = P.V' (A=P stored rows, B=vT'[e][kk'']); scatter un-permutes
//            rows into yT[n][c]
//  gemm_proj: out = Wproj @ y + bias + x (NT vs yT), fp32

typedef __attribute__((ext_vector_type(8))) short short8;
typedef __attribute__((ext_vector_type(4))) float f32x4;

typedef const __attribute__((address_space(1))) unsigned int* gas_ptr;
typedef __attribute__((address_space(3))) unsigned int* las_ptr;

#define ATTN_SCALE 0.08838834764831845f   // 128^-0.5

__device__ __forceinline__ unsigned short f2bf(float f) {
    union { float f; unsigned int u; } c; c.f = f;
    unsigned int u = c.u;
    u += 0x7fffu + ((u >> 16) & 1u);      // RNE
    return (unsigned short)(u >> 16);
}

__device__ __forceinline__ void gl_lds16(const void* g, void* l) {
    __builtin_amdgcn_global_load_lds((gas_ptr)(uintptr_t)g, (las_ptr)(uintptr_t)l,
                                     16, 0, 0);
}

// ---- v6 shared MFMA core: 128x128 C-tile, 4 waves, BK=32, 16x16x32 bf16 ----
template<int LDA, int LDB, int KDIM, bool PERMB = false>
__device__ __forceinline__ void mfma_core(
    const unsigned short* __restrict__ A,
    const unsigned short* __restrict__ B,
    int m0, int n0,
    unsigned short* __restrict__ sA, unsigned short* __restrict__ sB,
    f32x4 acc[4][4])
{
    const int tid  = threadIdx.x;
    const int lane = tid & 63, wave = tid >> 6;
    const int lr = lane >> 2, lc = lane & 3;       // staging: 16 rows x 4 chunks
    const int lcs = lc ^ ((lr >> 1) & 3);          // source-chunk swizzle
    const int wm = (wave & 1) * 64, wn = (wave >> 1) * 64;
    const int col = lane & 15, quad = lane >> 4;
    const int swz = (quad ^ ((col >> 1) & 3)) * 8; // read-side swizzle (shorts)

    const unsigned short* ga = A + (size_t)(m0 + 32 * wave + lr) * LDA + lcs * 8;
    int rb0 = n0 + 32 * wave + lr;
    int rb1 = rb0 + 16;
    if (PERMB) {
        rb0 = 4 * (rb0 & 127) + (rb0 >> 7);
        rb1 = 4 * (rb1 & 127) + (rb1 >> 7);
    }
    const unsigned short* gb0 = B + (size_t)rb0 * LDB + lcs * 8;
    const unsigned short* gb1 = B + (size_t)rb1 * LDB + lcs * 8;

    const int wr0 = (32 * wave) * 32;              // wave-uniform LDS row bases
    const int wr1 = (32 * wave + 16) * 32;

    // prologue: stage K-step 0 into buffer 0
    gl_lds16(ga,            sA + wr0);
    gl_lds16(ga + 16 * LDA, sA + wr1);
    gl_lds16(gb0,           sB + wr0);
    gl_lds16(gb1,           sB + wr1);

    constexpr int NK = KDIM / 32;
    for (int kk = 0; kk < NK; ++kk) {
        const int bo = (kk & 1) * 4096;
        if (kk + 1 < NK) {
            const int nb = ((kk + 1) & 1) * 4096;
            const int k0 = (kk + 1) * 32;
            gl_lds16(ga + k0,            sA + nb + wr0);
            gl_lds16(ga + k0 + 16 * LDA, sA + nb + wr1);
            gl_lds16(gb0 + k0,           sB + nb + wr0);
            gl_lds16(gb1 + k0,           sB + nb + wr1);
            asm volatile("s_waitcnt vmcnt(4)" ::: "memory");
        } else {
            asm volatile("s_waitcnt vmcnt(0)" ::: "memory");
        }
        __builtin_amdgcn_s_barrier();
        asm volatile("" ::: "memory");
        __builtin_amdgcn_sched_barrier(0);

        const unsigned short* bA = sA + bo;
        const unsigned short* bB = sB + bo;
        short8 af[4], bfv[4];
        #pragma unroll
        for (int i = 0; i < 4; ++i)
            af[i] = *(const short8*)&bA[(wm + i * 16 + col) * 32 + swz];
        #pragma unroll
        for (int j = 0; j < 4; ++j)
            bfv[j] = *(const short8*)&bB[(wn + j * 16 + col) * 32 + swz];
        #pragma unroll
        for (int i = 0; i < 4; ++i)
            #pragma unroll
            for (int j = 0; j < 4; ++j)
                acc[i][j] = __builtin_amdgcn_mfma_f32_16x16x32_bf16(
                    af[i], bfv[j], acc[i][j], 0, 0, 0);

        __builtin_amdgcn_s_barrier();          // reads done before next stage
        asm volatile("" ::: "memory");
    }
}

// ---- prep: z<4 -> transpose x[b][c][n]->xT[b][n][c] bf16 ; z==4 -> W conv ----
__global__ __launch_bounds__(256)
void prep(const float* __restrict__ x,
          const float* __restrict__ Wq, const float* __restrict__ Wk,
          const float* __restrict__ Wv, const float* __restrict__ Wp,
          unsigned short* __restrict__ xT, unsigned short* __restrict__ Wb)
{
    if (blockIdx.z == 4) {
        const int idx = (blockIdx.y * 64 + blockIdx.x) * 256 + threadIdx.x; // 262144
        const int mat = idx >> 16;
        const int off = (idx & 65535) << 2;
        const float* src = (mat == 0 ? Wq : mat == 1 ? Wk : mat == 2 ? Wv : Wp) + off;
        const float4 f = *(const float4*)src;
        uint2 o;
        o.x = f2bf(f.x) | ((unsigned)f2bf(f.y) << 16);
        o.y = f2bf(f.z) | ((unsigned)f2bf(f.w) << 16);
        *(uint2*)&Wb[mat * 262144 + off] = o;
        return;
    }
    const int b = blockIdx.z;
    const int l = threadIdx.x & 63, w = threadIdx.x >> 6;
    const int n  = blockIdx.x * 64 + l;
    const int c0 = blockIdx.y * 32 + w * 8;
    const float* xp = x + (size_t)b * 2097152 + (size_t)c0 * 4096 + n;
    unsigned int p[4];
    #pragma unroll
    for (int j = 0; j < 4; ++j) {
        const unsigned short a  = f2bf(xp[(2 * j)     * 4096]);
        const unsigned short bb = f2bf(xp[(2 * j + 1) * 4096]);
        p[j] = a | ((unsigned)bb << 16);
    }
    uint4 v; v.x = p[0]; v.y = p[1]; v.z = p[2]; v.w = p[3];
    *(uint4*)&xT[(size_t)b * 2097152 + (size_t)n * 512 + c0] = v;
}

// ---- K1: q/k = W @ x -> frag-linear (stored rows); V -> vT'[e][kk''] ----
// Epilogues repack the 128x128 C-tile through LDS (aliased on staging) so
// every global store is a coalesced b128.
__global__ __launch_bounds__(256)
void gemm_qkv(const unsigned short* __restrict__ Wb,
              const unsigned short* __restrict__ xT,
              unsigned short* __restrict__ qb, unsigned short* __restrict__ kb,
              unsigned short* __restrict__ vT)
{
    __shared__ unsigned short sT[128 * 136];          // 34.8 KB, aliases staging
    unsigned short* sA = sT;                          // [2][128*32] = 8192
    unsigned short* sB = sT + 8192;                   // [2][128*32] = 8192

    const int z = blockIdx.z, wsel = z >> 2, b = z & 3;
    const unsigned short* A = Wb + wsel * 262144;
    const unsigned short* B = xT + (size_t)b * 2097152;
    const int m0 = blockIdx.y * 128, n0 = blockIdx.x * 128;

    f32x4 z4 = {0.f, 0.f, 0.f, 0.f};
    f32x4 acc[4][4];
    #pragma unroll
    for (int i = 0; i < 4; ++i)
        #pragma unroll
        for (int j = 0; j < 4; ++j) acc[i][j] = z4;

    mfma_core<512, 512, 512>(A, B, m0, n0, sA, sB, acc);

    __syncthreads();   // drain before overwriting aliased staging

    const int tid = threadIdx.x;
    const int lane = tid & 63, wave = tid >> 6;
    const int wm = (wave & 1) * 64, wn = (wave >> 1) * 64;
    const int col = lane & 15, quad = lane >> 4;
    const int h = m0 >> 7, s = n0 >> 10;

    if (wsel < 2) {
        // stage C-tile [rr][ee], pad 136
        #pragma unroll
        for (int i = 0; i < 4; ++i)
            #pragma unroll
            for (int r = 0; r < 4; ++r) {
                const int rr = wm + i * 16 + quad * 4 + r;
                #pragma unroll
                for (int j = 0; j < 4; ++j)
                    sT[rr * 136 + wn + j * 16 + col] = f2bf(acc[i][j][r]);
            }
        __syncthreads();
        // frag-linear: stored_row = s*128 + t (t = rr); for elem (t, e):
        // addr = ((s*8 + t>>4)*32 + e>>5)*512 + (((e>>3)&3)*16 + (t&15))*8 + (e&7)
        // Per k-iter: wave wv writes one whole 1KB frag (lane*16B).
        unsigned short* C = (wsel == 0 ? qb : kb)
                          + (size_t)(b * 4 + h) * 524288;
        const int bKc = (n0 & 1023) >> 5;
        const int u = tid & 15, v = (tid >> 4) & 3, wv = tid >> 6;
        unsigned short* dst = C + (size_t)(s * 256 + bKc + wv) * 512
                            + (v * 16 + u) * 8;
        const unsigned short* src = sT + u * 136 + wv * 32 + v * 8;
        #pragma unroll
        for (int k = 0; k < 8; ++k)
            *(uint4*)(dst + k * 16384) = *(const uint4*)(src + k * 2176);
    } else {
        // stage transposed [ee][rr] (vT col kk'' = s*128 + rr), pad 136
        #pragma unroll
        for (int i = 0; i < 4; ++i)
            #pragma unroll
            for (int r = 0; r < 4; ++r) {
                const int rr = wm + i * 16 + quad * 4 + r;
                #pragma unroll
                for (int j = 0; j < 4; ++j)
                    sT[(wn + j * 16 + col) * 136 + rr] = f2bf(acc[i][j][r]);
            }
        __syncthreads();
        const int e0 = n0 & 1023;
        unsigned short* dst = vT + (size_t)(b * 4 + h) * 524288 + s * 128;
        const int u = tid & 15, rsel = tid >> 4;
        #pragma unroll
        for (int k = 0; k < 8; ++k) {
            const int ee = rsel + k * 16;
            *(uint4*)&dst[(size_t)(e0 + ee) * 512 + u * 8] =
                *(const uint4*)&sT[ee * 136 + u * 8];
        }
    }
}

// ---- K2: fused S = Q.K^T (K=1024) + row softmax -> P bf16 (stored rows) ----
__global__ __launch_bounds__(512)
void gemm_qks(const unsigned short* __restrict__ qb,
              const unsigned short* __restrict__ kb,
              unsigned short* __restrict__ P)
{
    __shared__ float red[2][32][8];
    const int d = blockIdx.x;                         // 0..255
    const int flat = (d & 7) * 32 + (d >> 3);         // XCD-chunked remap
    const int rg = flat & 15, z = flat >> 4;          // row-group, slab
    const unsigned short* Aq = qb + (size_t)z * 524288;
    const unsigned short* Bk = kb + (size_t)z * 524288;
    unsigned short* Pz = P + (size_t)z * 262144;

    const int tid = threadIdx.x;
    const int lane = tid & 63, w = tid >> 6;
    const int col = lane & 15, quad = lane >> 4;

    const unsigned short* ap0 = Aq + (size_t)((rg * 2 + 0) * 32) * 512 + lane * 8;
    const unsigned short* ap1 = Aq + (size_t)((rg * 2 + 1) * 32) * 512 + lane * 8;
    const unsigned short* bp0 = Bk + (size_t)((w * 4 + 0) * 32) * 512 + lane * 8;
    const unsigned short* bp1 = bp0 + 16384;
    const unsigned short* bp2 = bp0 + 32768;
    const unsigned short* bp3 = bp0 + 49152;

    f32x4 z4 = {0.f, 0.f, 0.f, 0.f};
    f32x4 acc[2][4];
    #pragma unroll
    for (int f = 0; f < 2; ++f)
        #pragma unroll
        for (int g = 0; g < 4; ++g) acc[f][g] = z4;

    #pragma unroll 4
    for (int kk = 0; kk < 32; ++kk) {
        const int o = kk * 512;
        const short8 af0 = *(const short8*)(ap0 + o);
        const short8 af1 = *(const short8*)(ap1 + o);
        short8 bf[4];
        bf[0] = *(const short8*)(bp0 + o);
        bf[1] = *(const short8*)(bp1 + o);
        bf[2] = *(const short8*)(bp2 + o);
        bf[3] = *(const short8*)(bp3 + o);
        #pragma unroll
        for (int g = 0; g < 4; ++g)
            acc[0][g] = __builtin_amdgcn_mfma_f32_16x16x32_bf16(
                af0, bf[g], acc[0][g], 0, 0, 0);
        #pragma unroll
        for (int g = 0; g < 4; ++g)
            acc[1][g] = __builtin_amdgcn_mfma_f32_16x16x32_bf16(
                af1, bf[g], acc[1][g], 0, 0, 0);
    }

    // ---- fused softmax over full 512-wide rows ----
    float mx[2][4];
    #pragma unroll
    for (int f = 0; f < 2; ++f)
        #pragma unroll
        for (int r = 0; r < 4; ++r) {
            float m = acc[f][0][r];
            #pragma unroll
            for (int g = 1; g < 4; ++g) m = fmaxf(m, acc[f][g][r]);
            #pragma unroll
            for (int s = 1; s < 16; s <<= 1) m = fmaxf(m, __shfl_xor(m, s));
            mx[f][r] = m;
        }
    if (col == 0) {
        #pragma unroll
        for (int f = 0; f < 2; ++f)
            #pragma unroll
            for (int r = 0; r < 4; ++r)
                red[0][f * 16 + quad * 4 + r][w] = mx[f][r];
    }
    __syncthreads();
    float sm[2][4];
    #pragma unroll
    for (int f = 0; f < 2; ++f)
        #pragma unroll
        for (int r = 0; r < 4; ++r) {
            const int row = f * 16 + quad * 4 + r;
            float m = red[0][row][0];
            #pragma unroll
            for (int t = 1; t < 8; ++t) m = fmaxf(m, red[0][row][t]);
            float s = 0.f;
            #pragma unroll
            for (int g = 0; g < 4; ++g) {
                const float e = __expf((acc[f][g][r] - m) * ATTN_SCALE);
                acc[f][g][r] = e;
                s += e;
            }
            #pragma unroll
            for (int t = 1; t < 16; t <<= 1) s += __shfl_xor(s, t);
            sm[f][r] = s;
        }
    if (col == 0) {
        #pragma unroll
        for (int f = 0; f < 2; ++f)
            #pragma unroll
            for (int r = 0; r < 4; ++r)
                red[1][f * 16 + quad * 4 + r][w] = sm[f][r];
    }
    __syncthreads();
    #pragma unroll
    for (int f = 0; f < 2; ++f)
        #pragma unroll
        for (int r = 0; r < 4; ++r) {
            const int row = f * 16 + quad * 4 + r;
            float tot = red[1][row][0];
            #pragma unroll
            for (int t = 1; t < 8; ++t) tot += red[1][row][t];
            const float inv = 1.f / tot;
            unsigned short* op = Pz + (size_t)(rg * 32 + row) * 512
                               + w * 64 + col;
            #pragma unroll
            for (int g = 0; g < 4; ++g)
                op[g * 16] = f2bf(acc[f][g][r] * inv);
        }
}

// ---- K4: O = P V' per slab; un-permute rows, scatter into yT[n][c] ----
__global__ __launch_bounds__(256)
void gemm_pv(const unsigned short* __restrict__ Pb,
             const unsigned short* __restrict__ vT,
             unsigned short* __restrict__ yT)
{
    __shared__ unsigned short sT[128 * 136];          // 34816 B; aliases staging
    unsigned short* sA = sT;                          // [2][128*32] = 8192
    unsigned short* sB = sT + 8192;                   // [2][128*32] = 8192
    const int z = blockIdx.z, b = z >> 2, hh = z & 3;
    const unsigned short* A = Pb + (size_t)z * 262144;   // [512][512] stored rows
    const unsigned short* B = vT + (size_t)z * 524288;   // [1024][512] kk''-rows
    unsigned short* yTb = yT + (size_t)b * 2097152;
    const int m0 = blockIdx.y * 128;   // stored-row block (fixed s_blk = m0>>7)
    const int n0 = blockIdx.x * 128;   // e

    f32x4 z4 = {0.f, 0.f, 0.f, 0.f};
    f32x4 acc[4][4];
    #pragma unroll
    for (int i = 0; i < 4; ++i)
        #pragma unroll
        for (int j = 0; j < 4; ++j) acc[i][j] = z4;

    mfma_core<512, 512, 512>(A, B, m0, n0, sA, sB, acc);

    // full drain before overwriting the aliased staging buffers with D-tile
    __syncthreads();

    const int tid = threadIdx.x;
    const int lane = tid & 63, wave = tid >> 6;
    const int wm = (wave & 1) * 64, wn = (wave >> 1) * 64;
    const int col = lane & 15, quad = lane >> 4;

    // D tile -> LDS [stored-row local][e_local], pad 136
    #pragma unroll
    for (int i = 0; i < 4; ++i)
        #pragma unroll
        for (int r = 0; r < 4; ++r) {
            const int rr = wm + i * 16 + quad * 4 + r;
            #pragma unroll
            for (int j = 0; j < 4; ++j)
                sT[rr * 136 + wn + j * 16 + col] = f2bf(acc[i][j][r]);
        }
    __syncthreads();

    // pack 16-elem c-runs; stored row m0+qq_l -> actual qq = 4*qq_l + (m0>>7)
    // yT[(s8<<9) + qq][hh*128 + (n0>>3) + tt], tt=0..15
    const int sblk = m0 >> 7;
    #pragma unroll
    for (int k = 0; k < 4; ++k) {
        const int rid = k * 256 + tid;       // 0..1023
        const int qq_l = rid >> 3, s = rid & 7;
        const unsigned short* Trow = sT + qq_l * 136;
        unsigned int p[8];
        #pragma unroll
        for (int t = 0; t < 8; ++t) {
            const unsigned int a  = Trow[s + 8 * (2 * t)];
            const unsigned int bb = Trow[s + 8 * (2 * t + 1)];
            p[t] = a | (bb << 16);
        }
        const size_t base = (size_t)((s << 9) + 4 * qq_l + sblk) * 512
                          + hh * 128 + (n0 >> 3);
        uint4 lo; lo.x = p[0]; lo.y = p[1]; lo.z = p[2]; lo.w = p[3];
        uint4 hi; hi.x = p[4]; hi.y = p[5]; hi.z = p[6]; hi.w = p[7];
        *(uint4*)&yTb[base]     = lo;
        *(uint4*)&yTb[base + 8] = hi;
    }
}

// ---- K5: out = Wproj @ y + bias + x (NT vs yT), fp32 out ----
__global__ __launch_bounds__(256)
void gemm_proj(const unsigned short* __restrict__ Wpb,
               const unsigned short* __restrict__ yT,
               const float* __restrict__ bias, const float* __restrict__ x,
               float* __restrict__ out)
{
    __shared__ unsigned short sA[2 * 128 * 32], sB[2 * 128 * 32];
    const int b = blockIdx.z;
    const unsigned short* B = yT + (size_t)b * 2097152;  // [4096][512]
    const int m0 = blockIdx.y * 128, n0 = blockIdx.x * 128;

    f32x4 z4 = {0.f, 0.f, 0.f, 0.f};
    f32x4 acc[4][4];
    #pragma unroll
    for (int i = 0; i < 4; ++i)
        #pragma unroll
        for (int j = 0; j < 4; ++j) acc[i][j] = z4;

    mfma_core<512, 512, 512>(Wpb, B, m0, n0, sA, sB, acc);

    const int lane = threadIdx.x & 63, wave = threadIdx.x >> 6;
    const int wm = (wave & 1) * 64, wn = (wave >> 1) * 64;
    const int col = lane & 15, quad = lane >> 4;
    const size_t boff = (size_t)b * 2097152;
    #pragma unroll
    for (int i = 0; i < 4; ++i)
        #pragma unroll
        for (int r = 0; r < 4; ++r) {
            const int row = m0 + wm + i * 16 + quad * 4 + r;
            const float bi = bias[row];
            #pragma unroll
            for (int j = 0; j < 4; ++j) {
                const size_t idx = boff + (size_t)row * 4096 + n0 + wn + j * 16 + col;
                out[idx] = acc[i][j][r] + bi + x[idx];
            }
        }
}

extern "C" void kernel_launch(void* const* d_in, const int* in_sizes, int n_in,
                              void* d_out, int out_size, void* d_ws, size_t ws_size,
                              hipStream_t stream) {
    const float* x     = (const float*)d_in[0];
    const float* Wq    = (const float*)d_in[1];
    const float* Wk    = (const float*)d_in[2];
    const float* Wv    = (const float*)d_in[3];
    const float* Wproj = (const float*)d_in[4];
    const float* bproj = (const float*)d_in[5];
    float* out = (float*)d_out;

    char* w = (char*)d_ws;
    unsigned short* xT = (unsigned short*)(w + 0);          // 16 MB [b][n][c]
    unsigned short* qb = (unsigned short*)(w + 16777216);   // 16 MB frag-layout
    unsigned short* kb = (unsigned short*)(w + 33554432);   // 16 MB frag-layout
    unsigned short* vT = (unsigned short*)(w + 50331648);   // 16 MB [slab][e][kk'']
    unsigned short* Pb = (unsigned short*)(w + 100663296);  //  8 MB
    unsigned short* Wb = (unsigned short*)(w + 109051904);  //  2 MB
    unsigned short* yT = xT;   // xT dead after gemm_qkv

    prep        <<<dim3(64, 16, 5),  256, 0, stream>>>(x, Wq, Wk, Wv, Wproj, xT, Wb);
    gemm_qkv    <<<dim3(32, 4, 12),  256, 0, stream>>>(Wb, xT, qb, kb, vT);
    gemm_qks    <<<dim3(256),        512, 0, stream>>>(qb, kb, Pb);
    gemm_pv     <<<dim3(8, 4, 16),   256, 0, stream>>>(Pb, vT, yT);
    gemm_proj   <<<dim3(32, 4, 4),   256, 0, stream>>>(Wb + 3 * 262144, yT, bproj, x, out);
}